// Round 1
// baseline (1175.105 us; speedup 1.0000x reference)
//
#include <hip/hip_runtime.h>

#define E_EDGES 250000
#define NHRU 100000
#define NCH  40000
#define NGW  60000

typedef __attribute__((ext_vector_type(4))) float f32x4;
typedef __attribute__((ext_vector_type(8))) __bf16 bf16x8;

__device__ __forceinline__ float bf2f(short h) {
  unsigned u = ((unsigned)(unsigned short)h) << 16;
  return __builtin_bit_cast(float, u);
}
__device__ __forceinline__ short f2bf(float f) {
  unsigned u = __builtin_bit_cast(unsigned, f);
  u = u + 0x7fffu + ((u >> 16) & 1u);
  return (short)(u >> 16);
}

__device__ __forceinline__ void load_lds16(const void* g, void* lds) {
  __builtin_amdgcn_global_load_lds(
      (const __attribute__((address_space(1))) unsigned*)g,
      (__attribute__((address_space(3))) unsigned*)lds, 16, 0, 0);
}

// ---------------- fp32 -> bf16 convert ----------------
__global__ void cvt_kernel(const float* __restrict__ in, short* __restrict__ out, int n4) {
  int i = blockIdx.x * blockDim.x + threadIdx.x;
  if (i >= n4) return;
  float4 v = reinterpret_cast<const float4*>(in)[i];
  short4 o;
  o.x = f2bf(v.x); o.y = f2bf(v.y); o.z = f2bf(v.z); o.w = f2bf(v.w);
  reinterpret_cast<short4*>(out)[i] = o;
}

// ---------------- weight prep: transpose + bf16 + fold /3 ----------------
// Bt buffer layout (elems): gw[256][512] @0, ch1[256][1024] @131072,
// hru[256][512] @393216, ch2[256][1024] @524288.  bias: [4][256]
__global__ void prep_w(const float* __restrict__ Wl, const float* __restrict__ Wr,
                       const float* __restrict__ bs, short* __restrict__ Bt,
                       float* __restrict__ bias) {
  int i = blockIdx.x * blockDim.x + threadIdx.x;
  const float inv3 = 1.0f / 3.0f;
  if (i < 131072) {                       // gw: l=0,r=0
    int n = i >> 9, k = i & 511;
    float v = (k < 256) ? Wl[(0 * 256 + k) * 256 + n]
                        : Wr[(0 * 256 + (k - 256)) * 256 + n];
    Bt[i] = f2bf(v);
  } else if (i < 393216) {                // ch l=0: r=1,2,3 then Wr-sum, all /3
    int j = i - 131072;
    int n = j >> 10, k = j & 1023;
    float v;
    if (k < 768) {
      int r = 1 + (k >> 8), kk = k & 255;
      v = Wl[((0 * 5 + r) * 256 + kk) * 256 + n] * inv3;
    } else {
      int kk = k - 768;
      v = (Wr[((0 * 5 + 1) * 256 + kk) * 256 + n] +
           Wr[((0 * 5 + 2) * 256 + kk) * 256 + n] +
           Wr[((0 * 5 + 3) * 256 + kk) * 256 + n]) * inv3;
    }
    Bt[i] = f2bf(v);
  } else if (i < 524288) {                // hru: l=0,r=4
    int j = i - 393216;
    int n = j >> 9, k = j & 511;
    float v = (k < 256) ? Wl[((0 * 5 + 4) * 256 + k) * 256 + n]
                        : Wr[((0 * 5 + 4) * 256 + (k - 256)) * 256 + n];
    Bt[i] = f2bf(v);
  } else if (i < 786432) {                // ch l=1
    int j = i - 524288;
    int n = j >> 10, k = j & 1023;
    float v;
    if (k < 768) {
      int r = 1 + (k >> 8), kk = k & 255;
      v = Wl[((5 + r) * 256 + kk) * 256 + n] * inv3;
    } else {
      int kk = k - 768;
      v = (Wr[((5 + 1) * 256 + kk) * 256 + n] +
           Wr[((5 + 2) * 256 + kk) * 256 + n] +
           Wr[((5 + 3) * 256 + kk) * 256 + n]) * inv3;
    }
    Bt[i] = f2bf(v);
  } else if (i < 787456) {                // biases
    int j = i - 786432;
    int g = j >> 8, n = j & 255;
    float v;
    if (g == 0)      v = bs[n];                                        // l0 r0
    else if (g == 1) v = (bs[256 + n] + bs[512 + n] + bs[768 + n]) * inv3;   // l0 ch
    else if (g == 2) v = bs[1024 + n];                                 // l0 r4
    else             v = (bs[1280 + 256 + n] + bs[1280 + 512 + n] + bs[1280 + 768 + n]) * inv3; // l1 ch
    bias[j] = v;
  }
}

// ---------------- CSR build ----------------
struct P5 { const int* p[5]; };

__global__ void count_kernel(P5 dst, int* __restrict__ cnt) {
  const int COFF[5] = {0, 60000, 100000, 140000, 180000};
  int r = blockIdx.y;
  int e = blockIdx.x * blockDim.x + threadIdx.x;
  if (e < E_EDGES) atomicAdd(&cnt[COFF[r] + dst.p[r][e]], 1);
}

__global__ void scan_kernel(const int* __restrict__ cnt, int* __restrict__ rp,
                            int* __restrict__ cur) {
  const int NREL[5] = {60000, 40000, 40000, 40000, 100000};
  const int COFF[5] = {0, 60000, 100000, 140000, 180000};
  const int ROFF[5] = {0, 60001, 100002, 140003, 180004};
  int r = blockIdx.x;
  int n = NREL[r];
  const int* c = cnt + COFF[r];
  int* rpp = rp + ROFF[r];
  int* cup = cur + COFF[r];
  int t = threadIdx.x;
  int chunk = (n + 1023) >> 10;
  int beg = t * chunk;
  int end = beg + chunk; if (end > n) end = n;
  int s = 0;
  for (int i = beg; i < end && i >= 0; ++i) s += c[i];
  __shared__ int lds[1024];
  lds[t] = s;
  __syncthreads();
  for (int o = 1; o < 1024; o <<= 1) {
    int add = (t >= o) ? lds[t - o] : 0;
    __syncthreads();
    lds[t] += add;
    __syncthreads();
  }
  int run = (t == 0) ? 0 : lds[t - 1];
  for (int i = beg; i < end; ++i) { rpp[i] = run; cup[i] = run; run += c[i]; }
  if (end == n && beg <= n) rpp[n] = run;
}

__global__ void fill_kernel(P5 src, P5 dst, int* __restrict__ cur, int* __restrict__ ssrc) {
  const int COFF[5] = {0, 60000, 100000, 140000, 180000};
  int r = blockIdx.y;
  int e = blockIdx.x * blockDim.x + threadIdx.x;
  if (e < E_EDGES) {
    int d = dst.p[r][e];
    int idx = atomicAdd(&cur[COFF[r] + d], 1);
    ssrc[r * E_EDGES + idx] = src.p[r][e];
  }
}

// ---------------- mean aggregation: one wave per dst row ----------------
__global__ void agg_kernel(const short* __restrict__ xs, const int* __restrict__ rp,
                           const int* __restrict__ ssrc, short* __restrict__ outb,
                           int n_dst) {
  int wv = (blockIdx.x * blockDim.x + threadIdx.x) >> 6;
  int lane = threadIdx.x & 63;
  if (wv >= n_dst) return;
  int lo = rp[wv], hi = rp[wv + 1];
  float a0 = 0.f, a1 = 0.f, a2 = 0.f, a3 = 0.f;
  for (int e = lo; e < hi; ++e) {
    int s = ssrc[e];
    short4 v = *reinterpret_cast<const short4*>(xs + (size_t)s * 256 + (lane << 2));
    a0 += bf2f(v.x); a1 += bf2f(v.y); a2 += bf2f(v.z); a3 += bf2f(v.w);
  }
  int c = hi - lo; if (c < 1) c = 1;
  float inv = 1.0f / (float)c;
  short4 o;
  o.x = f2bf(a0 * inv); o.y = f2bf(a1 * inv); o.z = f2bf(a2 * inv); o.w = f2bf(a3 * inv);
  *reinterpret_cast<short4*>(outb + (size_t)wv * 256 + (lane << 2)) = o;
}

// ---------------- bf16 MFMA GEMM: out = ReLU([srcs…] @ Bt^T + bias) ----------------
// A = virtual concat of up to 4 sources, each [*][256] bf16 row-major.
// Bt = [256][K] bf16 (pre-transposed weights). N=256 fixed. BM=BN=128, BK=64.
struct Srcs4 { const short* s[4]; };

__global__ __launch_bounds__(256) void gemm_bt(
    Srcs4 srcs, const short* __restrict__ Bt, const float* __restrict__ bias,
    int M, int K, short* __restrict__ outb, float* __restrict__ outf) {
  __shared__ short Asm[128 * 64];
  __shared__ short Bsm[128 * 64];
  const int tid = threadIdx.x;
  const int lane = tid & 63;
  const int w = tid >> 6;
  const int wr = w >> 1, wc = w & 1;
  const int m0 = blockIdx.x * 128;
  const int n0 = blockIdx.y * 128;

  f32x4 acc[4][4];
#pragma unroll
  for (int i = 0; i < 4; ++i)
#pragma unroll
    for (int j = 0; j < 4; ++j) acc[i][j] = (f32x4){0.f, 0.f, 0.f, 0.f};

  for (int k0 = 0; k0 < K; k0 += 64) {
    const short* Aq = srcs.s[k0 >> 8];
    const int kc = k0 & 255;
#pragma unroll
    for (int rr = 0; rr < 4; ++rr) {
      const int rbase = w * 32 + rr * 8;
      const int row = rbase + (lane >> 3);
      const int cs = ((lane & 7) ^ (row & 7)) << 3;   // pre-swizzled source chunk
      int gr = m0 + row; gr = gr < M ? gr : M - 1;
      load_lds16(Aq + (size_t)gr * 256 + kc + cs, &Asm[rbase * 64]);
      load_lds16(Bt + (size_t)(n0 + row) * K + k0 + cs, &Bsm[rbase * 64]);
    }
    __syncthreads();
#pragma unroll
    for (int h = 0; h < 2; ++h) {
      const int cg = (h << 2) + (lane >> 4);          // logical 16B chunk 0..7
      bf16x8 af[4], bfr[4];
#pragma unroll
      for (int mi = 0; mi < 4; ++mi) {
        const int r = wr * 64 + mi * 16 + (lane & 15);
        af[mi] = *reinterpret_cast<const bf16x8*>(&Asm[r * 64 + ((cg ^ (r & 7)) << 3)]);
      }
#pragma unroll
      for (int nj = 0; nj < 4; ++nj) {
        const int r = wc * 64 + nj * 16 + (lane & 15);
        bfr[nj] = *reinterpret_cast<const bf16x8*>(&Bsm[r * 64 + ((cg ^ (r & 7)) << 3)]);
      }
#pragma unroll
      for (int mi = 0; mi < 4; ++mi)
#pragma unroll
        for (int nj = 0; nj < 4; ++nj)
          acc[mi][nj] = __builtin_amdgcn_mfma_f32_16x16x32_bf16(af[mi], bfr[nj], acc[mi][nj], 0, 0, 0);
    }
    __syncthreads();
  }

  const int rb = (lane >> 4) << 2;
  const int cl = lane & 15;
#pragma unroll
  for (int mi = 0; mi < 4; ++mi) {
#pragma unroll
    for (int nj = 0; nj < 4; ++nj) {
      const int col = n0 + wc * 64 + nj * 16 + cl;
      const float bv = bias[col];
#pragma unroll
      for (int j = 0; j < 4; ++j) {
        const int row = m0 + wr * 64 + mi * 16 + rb + j;
        if (row < M) {
          float v = acc[mi][nj][j] + bv;
          v = fmaxf(v, 0.0f);
          if (outf) outf[(size_t)row * 256 + col] = v;
          if (outb) outb[(size_t)row * 256 + col] = f2bf(v);
        }
      }
    }
  }
}

// ---------------- pooling + MLP ----------------
__device__ __forceinline__ int lower_bound(const int* a, int n, int v) {
  int lo = 0, hi = n;
  while (lo < hi) { int mid = (lo + hi) >> 1; if (a[mid] < v) lo = mid + 1; else hi = mid; }
  return lo;
}

__global__ void pool_kernel(const float* __restrict__ c2, const int* __restrict__ batch,
                            float* __restrict__ pooled) {
  int b = blockIdx.x;
  int lo = lower_bound(batch, NCH, b);
  int hi = lower_bound(batch, NCH, b + 1);
  int col = threadIdx.x;
  float s = 0.f;
  for (int r = lo; r < hi; ++r) s += c2[(size_t)r * 256 + col];
  int c = hi - lo; if (c < 1) c = 1;
  pooled[b * 256 + col] = s / (float)c;
}

__global__ void mlp_kernel(const float* __restrict__ pooled, const float* __restrict__ train,
                           const float* __restrict__ fc1w, const float* __restrict__ fc1b,
                           const float* __restrict__ fc2w, const float* __restrict__ fc2b,
                           float* __restrict__ out) {
  int b = blockIdx.x, t = threadIdx.x;
  __shared__ float x[288];
  __shared__ float hsm[128];
  x[t] = pooled[b * 256 + t];
  x[128 + t] = pooled[b * 256 + 128 + t];
  if (t < 32) x[256 + t] = train[b * 32 + t];
  __syncthreads();
  float s = fc1b[t];
  for (int i = 0; i < 288; ++i) s += x[i] * fc1w[i * 128 + t];
  hsm[t] = fmaxf(s, 0.f);
  __syncthreads();
  if (t < 16) {
    float o = fc2b[t];
    for (int i = 0; i < 128; ++i) o += hsm[i] * fc2w[i * 16 + t];
    out[b * 16 + t] = o;
  }
}

// ---------------- launch ----------------
extern "C" void kernel_launch(void* const* d_in, const int* in_sizes, int n_in,
                              void* d_out, int out_size, void* d_ws, size_t ws_size,
                              hipStream_t stream) {
  const float* x_hru = (const float*)d_in[0];
  const float* x_ch  = (const float*)d_in[1];
  const float* x_gw  = (const float*)d_in[2];
  const int* src_swgw = (const int*)d_in[3];
  const int* dst_swgw = (const int*)d_in[4];
  const int* src_hyd  = (const int*)d_in[5];
  const int* dst_hyd  = (const int*)d_in[6];
  const int* src_sw   = (const int*)d_in[7];
  const int* dst_sw   = (const int*)d_in[8];
  const int* src_gwsw = (const int*)d_in[9];
  const int* dst_gwsw = (const int*)d_in[10];
  const int* src_slf  = (const int*)d_in[11];
  const int* dst_slf  = (const int*)d_in[12];
  const int* batch    = (const int*)d_in[13];
  const float* train  = (const float*)d_in[14];
  const float* Wl     = (const float*)d_in[15];
  const float* Wr     = (const float*)d_in[16];
  const float* bs     = (const float*)d_in[17];
  const float* fc1w   = (const float*)d_in[18];
  const float* fc1b   = (const float*)d_in[19];
  const float* fc2w   = (const float*)d_in[20];
  const float* fc2b   = (const float*)d_in[21];
  float* out = (float*)d_out;

  char* ws = (char*)d_ws;
  size_t off = 0;
  auto alloc = [&](size_t bytes) -> void* {
    off = (off + 255) & ~(size_t)255;
    void* p = ws + off;
    off += bytes;
    return p;
  };

  short* xb0h = (short*)alloc((size_t)NHRU * 256 * 2);
  short* xb0c = (short*)alloc((size_t)NCH * 256 * 2);
  short* xb0g = (short*)alloc((size_t)NGW * 256 * 2);
  short* xb1h = (short*)alloc((size_t)NHRU * 256 * 2);
  short* xb1c = (short*)alloc((size_t)NCH * 256 * 2);
  short* xb1g = (short*)alloc((size_t)NGW * 256 * 2);
  short* agg_gw  = (short*)alloc((size_t)NGW * 256 * 2);
  short* agg_c0  = (short*)alloc((size_t)NCH * 256 * 2);
  short* agg_c1  = (short*)alloc((size_t)NCH * 256 * 2);
  short* agg_c2  = (short*)alloc((size_t)NCH * 256 * 2);
  short* agg_hru = (short*)alloc((size_t)NHRU * 256 * 2);
  float* c2f = (float*)alloc((size_t)NCH * 256 * 4);
  int* cnt  = (int*)alloc(280000 * 4);
  int* rp   = (int*)alloc(280005 * 4);
  int* cur  = (int*)alloc(280000 * 4);
  int* ssrc = (int*)alloc((size_t)5 * E_EDGES * 4);
  short* BtBuf = (short*)alloc(786432 * 2);
  float* biasBuf = (float*)alloc(1024 * 4);
  float* pooled = (float*)alloc(64 * 256 * 4);

  hipMemsetAsync(cnt, 0, 280000 * 4, stream);

  cvt_kernel<<<NHRU * 256 / 4 / 256, 256, 0, stream>>>(x_hru, xb0h, NHRU * 256 / 4);
  cvt_kernel<<<NCH * 256 / 4 / 256, 256, 0, stream>>>(x_ch, xb0c, NCH * 256 / 4);
  cvt_kernel<<<NGW * 256 / 4 / 256, 256, 0, stream>>>(x_gw, xb0g, NGW * 256 / 4);
  prep_w<<<(787456 + 255) / 256, 256, 0, stream>>>(Wl, Wr, bs, BtBuf, biasBuf);

  P5 dsts; dsts.p[0] = dst_swgw; dsts.p[1] = dst_hyd; dsts.p[2] = dst_sw;
  dsts.p[3] = dst_gwsw; dsts.p[4] = dst_slf;
  P5 srcs; srcs.p[0] = src_swgw; srcs.p[1] = src_hyd; srcs.p[2] = src_sw;
  srcs.p[3] = src_gwsw; srcs.p[4] = src_slf;

  dim3 eg((E_EDGES + 255) / 256, 5);
  count_kernel<<<eg, 256, 0, stream>>>(dsts, cnt);
  scan_kernel<<<5, 1024, 0, stream>>>(cnt, rp, cur);
  fill_kernel<<<eg, 256, 0, stream>>>(srcs, dsts, cur, ssrc);

  const int RP0 = 0, RP1 = 60001, RP2 = 100002, RP3 = 140003, RP4 = 180004;

  // layer 1 aggregations
  agg_kernel<<<(NGW + 3) / 4, 256, 0, stream>>>(xb0h, rp + RP0, ssrc + 0 * E_EDGES, agg_gw, NGW);
  agg_kernel<<<(NCH + 3) / 4, 256, 0, stream>>>(xb0c, rp + RP1, ssrc + 1 * E_EDGES, agg_c0, NCH);
  agg_kernel<<<(NCH + 3) / 4, 256, 0, stream>>>(xb0h, rp + RP2, ssrc + 2 * E_EDGES, agg_c1, NCH);
  agg_kernel<<<(NCH + 3) / 4, 256, 0, stream>>>(xb0g, rp + RP3, ssrc + 3 * E_EDGES, agg_c2, NCH);
  agg_kernel<<<(NHRU + 3) / 4, 256, 0, stream>>>(xb0h, rp + RP4, ssrc + 4 * E_EDGES, agg_hru, NHRU);

  // layer 1 GEMMs
  {
    Srcs4 s{}; s.s[0] = agg_gw; s.s[1] = xb0g;
    gemm_bt<<<dim3((NGW + 127) / 128, 2), 256, 0, stream>>>(s, BtBuf + 0, biasBuf + 0, NGW, 512, xb1g, nullptr);
  }
  {
    Srcs4 s{}; s.s[0] = agg_c0; s.s[1] = agg_c1; s.s[2] = agg_c2; s.s[3] = xb0c;
    gemm_bt<<<dim3((NCH + 127) / 128, 2), 256, 0, stream>>>(s, BtBuf + 131072, biasBuf + 256, NCH, 1024, xb1c, nullptr);
  }
  {
    Srcs4 s{}; s.s[0] = agg_hru; s.s[1] = xb0h;
    gemm_bt<<<dim3((NHRU + 127) / 128, 2), 256, 0, stream>>>(s, BtBuf + 393216, biasBuf + 512, NHRU, 512, xb1h, nullptr);
  }

  // layer 2 aggregations (only channel-dst relations matter)
  agg_kernel<<<(NCH + 3) / 4, 256, 0, stream>>>(xb1c, rp + RP1, ssrc + 1 * E_EDGES, agg_c0, NCH);
  agg_kernel<<<(NCH + 3) / 4, 256, 0, stream>>>(xb1h, rp + RP2, ssrc + 2 * E_EDGES, agg_c1, NCH);
  agg_kernel<<<(NCH + 3) / 4, 256, 0, stream>>>(xb1g, rp + RP3, ssrc + 3 * E_EDGES, agg_c2, NCH);

  // layer 2 channel GEMM -> fp32 c2
  {
    Srcs4 s{}; s.s[0] = agg_c0; s.s[1] = agg_c1; s.s[2] = agg_c2; s.s[3] = xb1c;
    gemm_bt<<<dim3((NCH + 127) / 128, 2), 256, 0, stream>>>(s, BtBuf + 524288, biasBuf + 768, NCH, 1024, nullptr, c2f);
  }

  pool_kernel<<<64, 256, 0, stream>>>(c2f, batch, pooled);
  mlp_kernel<<<64, 128, 0, stream>>>(pooled, train, fc1w, fc1b, fc2w, fc2b, out);

  (void)in_sizes; (void)n_in; (void)out_size; (void)ws_size;
}

// Round 2
// 966.488 us; speedup vs baseline: 1.2159x; 1.2159x over previous
//
#include <hip/hip_runtime.h>

#define E_EDGES 250000
#define NHRU 100000
#define NCH  40000
#define NGW  60000

typedef __attribute__((ext_vector_type(4))) float f32x4;
typedef __attribute__((ext_vector_type(8))) __bf16 bf16x8;

__device__ __forceinline__ float bf2f(short h) {
  unsigned u = ((unsigned)(unsigned short)h) << 16;
  return __builtin_bit_cast(float, u);
}
__device__ __forceinline__ short f2bf(float f) {
  unsigned u = __builtin_bit_cast(unsigned, f);
  u = u + 0x7fffu + ((u >> 16) & 1u);
  return (short)(u >> 16);
}

__device__ __forceinline__ void load_lds16(const void* g, void* lds) {
  __builtin_amdgcn_global_load_lds(
      (const __attribute__((address_space(1))) unsigned*)g,
      (__attribute__((address_space(3))) unsigned*)lds, 16, 0, 0);
}

// ---------------- fp32 -> bf16 convert ----------------
__global__ void cvt_kernel(const float* __restrict__ in, short* __restrict__ out, int n4) {
  int i = blockIdx.x * blockDim.x + threadIdx.x;
  if (i >= n4) return;
  float4 v = reinterpret_cast<const float4*>(in)[i];
  short4 o;
  o.x = f2bf(v.x); o.y = f2bf(v.y); o.z = f2bf(v.z); o.w = f2bf(v.w);
  reinterpret_cast<short4*>(out)[i] = o;
}

// ---------------- weight prep: transpose + bf16 + fold /3 ----------------
// Bt buffer layout (elems): gw[256][512] @0, ch1[256][1024] @131072,
// hru[256][512] @393216, ch2[256][1024] @524288.  bias: [4][256]
__global__ void prep_w(const float* __restrict__ Wl, const float* __restrict__ Wr,
                       const float* __restrict__ bs, short* __restrict__ Bt,
                       float* __restrict__ bias) {
  int i = blockIdx.x * blockDim.x + threadIdx.x;
  const float inv3 = 1.0f / 3.0f;
  if (i < 131072) {                       // gw: l=0,r=0
    int n = i >> 9, k = i & 511;
    float v = (k < 256) ? Wl[(0 * 256 + k) * 256 + n]
                        : Wr[(0 * 256 + (k - 256)) * 256 + n];
    Bt[i] = f2bf(v);
  } else if (i < 393216) {                // ch l=0: r=1,2,3 then Wr-sum, all /3
    int j = i - 131072;
    int n = j >> 10, k = j & 1023;
    float v;
    if (k < 768) {
      int r = 1 + (k >> 8), kk = k & 255;
      v = Wl[((0 * 5 + r) * 256 + kk) * 256 + n] * inv3;
    } else {
      int kk = k - 768;
      v = (Wr[((0 * 5 + 1) * 256 + kk) * 256 + n] +
           Wr[((0 * 5 + 2) * 256 + kk) * 256 + n] +
           Wr[((0 * 5 + 3) * 256 + kk) * 256 + n]) * inv3;
    }
    Bt[i] = f2bf(v);
  } else if (i < 524288) {                // hru: l=0,r=4
    int j = i - 393216;
    int n = j >> 9, k = j & 511;
    float v = (k < 256) ? Wl[((0 * 5 + 4) * 256 + k) * 256 + n]
                        : Wr[((0 * 5 + 4) * 256 + (k - 256)) * 256 + n];
    Bt[i] = f2bf(v);
  } else if (i < 786432) {                // ch l=1
    int j = i - 524288;
    int n = j >> 10, k = j & 1023;
    float v;
    if (k < 768) {
      int r = 1 + (k >> 8), kk = k & 255;
      v = Wl[((5 + r) * 256 + kk) * 256 + n] * inv3;
    } else {
      int kk = k - 768;
      v = (Wr[((5 + 1) * 256 + kk) * 256 + n] +
           Wr[((5 + 2) * 256 + kk) * 256 + n] +
           Wr[((5 + 3) * 256 + kk) * 256 + n]) * inv3;
    }
    Bt[i] = f2bf(v);
  } else if (i < 787456) {                // biases
    int j = i - 786432;
    int g = j >> 8, n = j & 255;
    float v;
    if (g == 0)      v = bs[n];                                        // l0 r0
    else if (g == 1) v = (bs[256 + n] + bs[512 + n] + bs[768 + n]) * inv3;   // l0 ch
    else if (g == 2) v = bs[1024 + n];                                 // l0 r4
    else             v = (bs[1280 + 256 + n] + bs[1280 + 512 + n] + bs[1280 + 768 + n]) * inv3; // l1 ch
    bias[j] = v;
  }
}

// ---------------- CSR build ----------------
struct P5 { const int* p[5]; };

__global__ void count_kernel(P5 dst, int* __restrict__ cnt) {
  const int COFF[5] = {0, 60000, 100000, 140000, 180000};
  int r = blockIdx.y;
  int e = blockIdx.x * blockDim.x + threadIdx.x;
  if (e < E_EDGES) atomicAdd(&cnt[COFF[r] + dst.p[r][e]], 1);
}

__global__ void scan_kernel(const int* __restrict__ cnt, int* __restrict__ rp,
                            int* __restrict__ cur) {
  const int NREL[5] = {60000, 40000, 40000, 40000, 100000};
  const int COFF[5] = {0, 60000, 100000, 140000, 180000};
  const int ROFF[5] = {0, 60001, 100002, 140003, 180004};
  int r = blockIdx.x;
  int n = NREL[r];
  const int* c = cnt + COFF[r];
  int* rpp = rp + ROFF[r];
  int* cup = cur + COFF[r];
  int t = threadIdx.x;
  int chunk = (n + 1023) >> 10;
  int beg = t * chunk;
  int end = beg + chunk; if (end > n) end = n;
  int s = 0;
  for (int i = beg; i < end && i >= 0; ++i) s += c[i];
  __shared__ int lds[1024];
  lds[t] = s;
  __syncthreads();
  for (int o = 1; o < 1024; o <<= 1) {
    int add = (t >= o) ? lds[t - o] : 0;
    __syncthreads();
    lds[t] += add;
    __syncthreads();
  }
  int run = (t == 0) ? 0 : lds[t - 1];
  for (int i = beg; i < end; ++i) { rpp[i] = run; cup[i] = run; run += c[i]; }
  if (end == n && beg <= n) rpp[n] = run;
}

__global__ void fill_kernel(P5 src, P5 dst, int* __restrict__ cur, int* __restrict__ ssrc) {
  const int COFF[5] = {0, 60000, 100000, 140000, 180000};
  int r = blockIdx.y;
  int e = blockIdx.x * blockDim.x + threadIdx.x;
  if (e < E_EDGES) {
    int d = dst.p[r][e];
    int idx = atomicAdd(&cur[COFF[r] + d], 1);
    ssrc[r * E_EDGES + idx] = src.p[r][e];
  }
}

// ---------------- mean aggregation: one wave per dst row ----------------
__global__ void agg_kernel(const short* __restrict__ xs, const int* __restrict__ rp,
                           const int* __restrict__ ssrc, short* __restrict__ outb,
                           int n_dst) {
  int wv = (blockIdx.x * blockDim.x + threadIdx.x) >> 6;
  int lane = threadIdx.x & 63;
  if (wv >= n_dst) return;
  int lo = rp[wv], hi = rp[wv + 1];
  float a0 = 0.f, a1 = 0.f, a2 = 0.f, a3 = 0.f;
  for (int e = lo; e < hi; ++e) {
    int s = ssrc[e];
    short4 v = *reinterpret_cast<const short4*>(xs + (size_t)s * 256 + (lane << 2));
    a0 += bf2f(v.x); a1 += bf2f(v.y); a2 += bf2f(v.z); a3 += bf2f(v.w);
  }
  int c = hi - lo; if (c < 1) c = 1;
  float inv = 1.0f / (float)c;
  short4 o;
  o.x = f2bf(a0 * inv); o.y = f2bf(a1 * inv); o.z = f2bf(a2 * inv); o.w = f2bf(a3 * inv);
  *reinterpret_cast<short4*>(outb + (size_t)wv * 256 + (lane << 2)) = o;
}

// ---------------- bf16 MFMA GEMM: out = ReLU([srcs…] @ Bt^T + bias) ----------------
// A = virtual concat of up to 4 sources, each [*][256] bf16 row-major.
// Bt = [256][K] bf16 (pre-transposed weights). N=256 fixed. BM=BN=128, BK=64.
struct Srcs4 { const short* s[4]; };

__global__ __launch_bounds__(256) void gemm_bt(
    Srcs4 srcs, const short* __restrict__ Bt, const float* __restrict__ bias,
    int M, int K, short* __restrict__ outb, float* __restrict__ outf) {
  __shared__ short Asm[128 * 64];
  __shared__ short Bsm[128 * 64];
  const int tid = threadIdx.x;
  const int lane = tid & 63;
  const int w = tid >> 6;
  const int wr = w >> 1, wc = w & 1;
  const int m0 = blockIdx.x * 128;
  const int n0 = blockIdx.y * 128;

  f32x4 acc[4][4];
#pragma unroll
  for (int i = 0; i < 4; ++i)
#pragma unroll
    for (int j = 0; j < 4; ++j) acc[i][j] = (f32x4){0.f, 0.f, 0.f, 0.f};

  for (int k0 = 0; k0 < K; k0 += 64) {
    const short* Aq = srcs.s[k0 >> 8];
    const int kc = k0 & 255;
#pragma unroll
    for (int rr = 0; rr < 4; ++rr) {
      const int rbase = w * 32 + rr * 8;
      const int row = rbase + (lane >> 3);
      const int cs = ((lane & 7) ^ (row & 7)) << 3;   // pre-swizzled source chunk
      int gr = m0 + row; gr = gr < M ? gr : M - 1;
      load_lds16(Aq + (size_t)gr * 256 + kc + cs, &Asm[rbase * 64]);
      load_lds16(Bt + (size_t)(n0 + row) * K + k0 + cs, &Bsm[rbase * 64]);
    }
    __syncthreads();
#pragma unroll
    for (int h = 0; h < 2; ++h) {
      const int cg = (h << 2) + (lane >> 4);          // logical 16B chunk 0..7
      bf16x8 af[4], bfr[4];
#pragma unroll
      for (int mi = 0; mi < 4; ++mi) {
        const int r = wr * 64 + mi * 16 + (lane & 15);
        af[mi] = *reinterpret_cast<const bf16x8*>(&Asm[r * 64 + ((cg ^ (r & 7)) << 3)]);
      }
#pragma unroll
      for (int nj = 0; nj < 4; ++nj) {
        const int r = wc * 64 + nj * 16 + (lane & 15);
        bfr[nj] = *reinterpret_cast<const bf16x8*>(&Bsm[r * 64 + ((cg ^ (r & 7)) << 3)]);
      }
#pragma unroll
      for (int mi = 0; mi < 4; ++mi)
#pragma unroll
        for (int nj = 0; nj < 4; ++nj)
          acc[mi][nj] = __builtin_amdgcn_mfma_f32_16x16x32_bf16(af[mi], bfr[nj], acc[mi][nj], 0, 0, 0);
    }
    __syncthreads();
  }

  const int rb = (lane >> 4) << 2;
  const int cl = lane & 15;
#pragma unroll
  for (int mi = 0; mi < 4; ++mi) {
#pragma unroll
    for (int nj = 0; nj < 4; ++nj) {
      const int col = n0 + wc * 64 + nj * 16 + cl;
      const float bv = bias[col];
#pragma unroll
      for (int j = 0; j < 4; ++j) {
        const int row = m0 + wr * 64 + mi * 16 + rb + j;
        if (row < M) {
          float v = acc[mi][nj][j] + bv;
          v = fmaxf(v, 0.0f);
          if (outf) outf[(size_t)row * 256 + col] = v;
          if (outb) outb[(size_t)row * 256 + col] = f2bf(v);
        }
      }
    }
  }
}

// ---------------- pooling (two-stage) + MLP ----------------
__device__ __forceinline__ int lower_bound(const int* a, int n, int v) {
  int lo = 0, hi = n;
  while (lo < hi) { int mid = (lo + hi) >> 1; if (a[mid] < v) lo = mid + 1; else hi = mid; }
  return lo;
}

// 625 blocks x 64 rows each; batch is sorted, so rows form runs. Accumulate
// per-column in registers across a run, one atomicAdd per (run, column).
__global__ void pool_partial(const float* __restrict__ c2, const int* __restrict__ batch,
                             float* __restrict__ pooled_sum) {
  int r0 = blockIdx.x * 64;
  int t = threadIdx.x;
  float acc = 0.f;
  int prevb = batch[r0];
  for (int i = 0; i < 64; ++i) {
    int r = r0 + i;
    int b = batch[r];
    if (b != prevb) {
      atomicAdd(&pooled_sum[prevb * 256 + t], acc);
      acc = 0.f; prevb = b;
    }
    acc += c2[(size_t)r * 256 + t];
  }
  atomicAdd(&pooled_sum[prevb * 256 + t], acc);
}

__global__ void mlp_kernel(const float* __restrict__ pooled_sum, const int* __restrict__ batch,
                           const float* __restrict__ train,
                           const float* __restrict__ fc1w, const float* __restrict__ fc1b,
                           const float* __restrict__ fc2w, const float* __restrict__ fc2b,
                           float* __restrict__ out) {
  int b = blockIdx.x, t = threadIdx.x;
  __shared__ float x[288];
  __shared__ float hsm[128];
  __shared__ float sinv;
  if (t == 0) {
    int lo = lower_bound(batch, NCH, b);
    int hi = lower_bound(batch, NCH, b + 1);
    int c = hi - lo; if (c < 1) c = 1;
    sinv = 1.0f / (float)c;
  }
  __syncthreads();
  float inv = sinv;
  x[t] = pooled_sum[b * 256 + t] * inv;
  x[128 + t] = pooled_sum[b * 256 + 128 + t] * inv;
  if (t < 32) x[256 + t] = train[b * 32 + t];
  __syncthreads();
  float s = fc1b[t];
  for (int i = 0; i < 288; ++i) s += x[i] * fc1w[i * 128 + t];
  hsm[t] = fmaxf(s, 0.f);
  __syncthreads();
  if (t < 16) {
    float o = fc2b[t];
    for (int i = 0; i < 128; ++i) o += hsm[i] * fc2w[i * 16 + t];
    out[b * 16 + t] = o;
  }
}

// ---------------- launch ----------------
extern "C" void kernel_launch(void* const* d_in, const int* in_sizes, int n_in,
                              void* d_out, int out_size, void* d_ws, size_t ws_size,
                              hipStream_t stream) {
  const float* x_hru = (const float*)d_in[0];
  const float* x_ch  = (const float*)d_in[1];
  const float* x_gw  = (const float*)d_in[2];
  const int* src_swgw = (const int*)d_in[3];
  const int* dst_swgw = (const int*)d_in[4];
  const int* src_hyd  = (const int*)d_in[5];
  const int* dst_hyd  = (const int*)d_in[6];
  const int* src_sw   = (const int*)d_in[7];
  const int* dst_sw   = (const int*)d_in[8];
  const int* src_gwsw = (const int*)d_in[9];
  const int* dst_gwsw = (const int*)d_in[10];
  const int* src_slf  = (const int*)d_in[11];
  const int* dst_slf  = (const int*)d_in[12];
  const int* batch    = (const int*)d_in[13];
  const float* train  = (const float*)d_in[14];
  const float* Wl     = (const float*)d_in[15];
  const float* Wr     = (const float*)d_in[16];
  const float* bs     = (const float*)d_in[17];
  const float* fc1w   = (const float*)d_in[18];
  const float* fc1b   = (const float*)d_in[19];
  const float* fc2w   = (const float*)d_in[20];
  const float* fc2b   = (const float*)d_in[21];
  float* out = (float*)d_out;

  char* ws = (char*)d_ws;
  size_t off = 0;
  auto alloc = [&](size_t bytes) -> void* {
    off = (off + 255) & ~(size_t)255;
    void* p = ws + off;
    off += bytes;
    return p;
  };

  short* xb0h = (short*)alloc((size_t)NHRU * 256 * 2);
  short* xb0c = (short*)alloc((size_t)NCH * 256 * 2);
  short* xb0g = (short*)alloc((size_t)NGW * 256 * 2);
  short* xb1h = (short*)alloc((size_t)NHRU * 256 * 2);
  short* xb1c = (short*)alloc((size_t)NCH * 256 * 2);
  short* xb1g = (short*)alloc((size_t)NGW * 256 * 2);
  short* agg_gw  = (short*)alloc((size_t)NGW * 256 * 2);
  short* agg_c0  = (short*)alloc((size_t)NCH * 256 * 2);
  short* agg_c1  = (short*)alloc((size_t)NCH * 256 * 2);
  short* agg_c2  = (short*)alloc((size_t)NCH * 256 * 2);
  short* agg_hru = (short*)alloc((size_t)NHRU * 256 * 2);
  float* c2f = (float*)alloc((size_t)NCH * 256 * 4);
  int* cnt  = (int*)alloc(280000 * 4);
  int* rp   = (int*)alloc(280005 * 4);
  int* cur  = (int*)alloc(280000 * 4);
  int* ssrc = (int*)alloc((size_t)5 * E_EDGES * 4);
  short* BtBuf = (short*)alloc(786432 * 2);
  float* biasBuf = (float*)alloc(1024 * 4);
  float* pooled_sum = (float*)alloc(64 * 256 * 4);

  hipMemsetAsync(cnt, 0, 280000 * 4, stream);
  hipMemsetAsync(pooled_sum, 0, 64 * 256 * 4, stream);

  cvt_kernel<<<NHRU * 256 / 4 / 256, 256, 0, stream>>>(x_hru, xb0h, NHRU * 256 / 4);
  cvt_kernel<<<NCH * 256 / 4 / 256, 256, 0, stream>>>(x_ch, xb0c, NCH * 256 / 4);
  cvt_kernel<<<NGW * 256 / 4 / 256, 256, 0, stream>>>(x_gw, xb0g, NGW * 256 / 4);
  prep_w<<<(787456 + 255) / 256, 256, 0, stream>>>(Wl, Wr, bs, BtBuf, biasBuf);

  P5 dsts; dsts.p[0] = dst_swgw; dsts.p[1] = dst_hyd; dsts.p[2] = dst_sw;
  dsts.p[3] = dst_gwsw; dsts.p[4] = dst_slf;
  P5 srcs; srcs.p[0] = src_swgw; srcs.p[1] = src_hyd; srcs.p[2] = src_sw;
  srcs.p[3] = src_gwsw; srcs.p[4] = src_slf;

  dim3 eg((E_EDGES + 255) / 256, 5);
  count_kernel<<<eg, 256, 0, stream>>>(dsts, cnt);
  scan_kernel<<<5, 1024, 0, stream>>>(cnt, rp, cur);
  fill_kernel<<<eg, 256, 0, stream>>>(srcs, dsts, cur, ssrc);

  const int RP0 = 0, RP1 = 60001, RP2 = 100002, RP3 = 140003, RP4 = 180004;

  // layer 1 aggregations
  agg_kernel<<<(NGW + 3) / 4, 256, 0, stream>>>(xb0h, rp + RP0, ssrc + 0 * E_EDGES, agg_gw, NGW);
  agg_kernel<<<(NCH + 3) / 4, 256, 0, stream>>>(xb0c, rp + RP1, ssrc + 1 * E_EDGES, agg_c0, NCH);
  agg_kernel<<<(NCH + 3) / 4, 256, 0, stream>>>(xb0h, rp + RP2, ssrc + 2 * E_EDGES, agg_c1, NCH);
  agg_kernel<<<(NCH + 3) / 4, 256, 0, stream>>>(xb0g, rp + RP3, ssrc + 3 * E_EDGES, agg_c2, NCH);
  agg_kernel<<<(NHRU + 3) / 4, 256, 0, stream>>>(xb0h, rp + RP4, ssrc + 4 * E_EDGES, agg_hru, NHRU);

  // layer 1 GEMMs
  {
    Srcs4 s{}; s.s[0] = agg_gw; s.s[1] = xb0g;
    gemm_bt<<<dim3((NGW + 127) / 128, 2), 256, 0, stream>>>(s, BtBuf + 0, biasBuf + 0, NGW, 512, xb1g, nullptr);
  }
  {
    Srcs4 s{}; s.s[0] = agg_c0; s.s[1] = agg_c1; s.s[2] = agg_c2; s.s[3] = xb0c;
    gemm_bt<<<dim3((NCH + 127) / 128, 2), 256, 0, stream>>>(s, BtBuf + 131072, biasBuf + 256, NCH, 1024, xb1c, nullptr);
  }
  {
    Srcs4 s{}; s.s[0] = agg_hru; s.s[1] = xb0h;
    gemm_bt<<<dim3((NHRU + 127) / 128, 2), 256, 0, stream>>>(s, BtBuf + 393216, biasBuf + 512, NHRU, 512, xb1h, nullptr);
  }

  // layer 2 aggregations (only channel-dst relations matter)
  agg_kernel<<<(NCH + 3) / 4, 256, 0, stream>>>(xb1c, rp + RP1, ssrc + 1 * E_EDGES, agg_c0, NCH);
  agg_kernel<<<(NCH + 3) / 4, 256, 0, stream>>>(xb1h, rp + RP2, ssrc + 2 * E_EDGES, agg_c1, NCH);
  agg_kernel<<<(NCH + 3) / 4, 256, 0, stream>>>(xb1g, rp + RP3, ssrc + 3 * E_EDGES, agg_c2, NCH);

  // layer 2 channel GEMM -> fp32 c2
  {
    Srcs4 s{}; s.s[0] = agg_c0; s.s[1] = agg_c1; s.s[2] = agg_c2; s.s[3] = xb1c;
    gemm_bt<<<dim3((NCH + 127) / 128, 2), 256, 0, stream>>>(s, BtBuf + 524288, biasBuf + 768, NCH, 1024, nullptr, c2f);
  }

  pool_partial<<<625, 256, 0, stream>>>(c2f, batch, pooled_sum);
  mlp_kernel<<<64, 128, 0, stream>>>(pooled_sum, batch, train, fc1w, fc1b, fc2w, fc2b, out);

  (void)in_sizes; (void)n_in; (void)out_size; (void)ws_size;
}

// Round 3
// 762.912 us; speedup vs baseline: 1.5403x; 1.2668x over previous
//
#include <hip/hip_runtime.h>

#define E_EDGES 250000
#define NHRU 100000
#define NCH  40000
#define NGW  60000
#define NCNT 280000
#define NBLK_SCAN 1094

typedef __attribute__((ext_vector_type(4))) float f32x4;
typedef __attribute__((ext_vector_type(8))) __bf16 bf16x8;

__device__ __forceinline__ float bf2f(short h) {
  unsigned u = ((unsigned)(unsigned short)h) << 16;
  return __builtin_bit_cast(float, u);
}
__device__ __forceinline__ short f2bf(float f) {
  unsigned u = __builtin_bit_cast(unsigned, f);
  u = u + 0x7fffu + ((u >> 16) & 1u);
  return (short)(u >> 16);
}

__device__ __forceinline__ void load_lds16(const void* g, void* lds) {
  __builtin_amdgcn_global_load_lds(
      (const __attribute__((address_space(1))) unsigned*)g,
      (__attribute__((address_space(3))) unsigned*)lds, 16, 0, 0);
}

// ---------------- fp32 -> bf16 convert ----------------
__global__ void cvt_kernel(const float* __restrict__ in, short* __restrict__ out, int n4) {
  int i = blockIdx.x * blockDim.x + threadIdx.x;
  if (i >= n4) return;
  float4 v = reinterpret_cast<const float4*>(in)[i];
  short4 o;
  o.x = f2bf(v.x); o.y = f2bf(v.y); o.z = f2bf(v.z); o.w = f2bf(v.w);
  reinterpret_cast<short4*>(out)[i] = o;
}

// ---------------- weight prep: transpose + bf16 + fold /3 ----------------
// Bt buffer layout (elems): gw[256][512] @0, ch1[256][1024] @131072,
// hru[256][512] @393216, ch2[256][1024] @524288.  bias: [4][256]
__global__ void prep_w(const float* __restrict__ Wl, const float* __restrict__ Wr,
                       const float* __restrict__ bs, short* __restrict__ Bt,
                       float* __restrict__ bias) {
  int i = blockIdx.x * blockDim.x + threadIdx.x;
  const float inv3 = 1.0f / 3.0f;
  if (i < 131072) {                       // gw: l=0,r=0
    int n = i >> 9, k = i & 511;
    float v = (k < 256) ? Wl[(0 * 256 + k) * 256 + n]
                        : Wr[(0 * 256 + (k - 256)) * 256 + n];
    Bt[i] = f2bf(v);
  } else if (i < 393216) {                // ch l=0: r=1,2,3 then Wr-sum, all /3
    int j = i - 131072;
    int n = j >> 10, k = j & 1023;
    float v;
    if (k < 768) {
      int r = 1 + (k >> 8), kk = k & 255;
      v = Wl[((0 * 5 + r) * 256 + kk) * 256 + n] * inv3;
    } else {
      int kk = k - 768;
      v = (Wr[((0 * 5 + 1) * 256 + kk) * 256 + n] +
           Wr[((0 * 5 + 2) * 256 + kk) * 256 + n] +
           Wr[((0 * 5 + 3) * 256 + kk) * 256 + n]) * inv3;
    }
    Bt[i] = f2bf(v);
  } else if (i < 524288) {                // hru: l=0,r=4
    int j = i - 393216;
    int n = j >> 9, k = j & 511;
    float v = (k < 256) ? Wl[((0 * 5 + 4) * 256 + k) * 256 + n]
                        : Wr[((0 * 5 + 4) * 256 + (k - 256)) * 256 + n];
    Bt[i] = f2bf(v);
  } else if (i < 786432) {                // ch l=1
    int j = i - 524288;
    int n = j >> 10, k = j & 1023;
    float v;
    if (k < 768) {
      int r = 1 + (k >> 8), kk = k & 255;
      v = Wl[((5 + r) * 256 + kk) * 256 + n] * inv3;
    } else {
      int kk = k - 768;
      v = (Wr[((5 + 1) * 256 + kk) * 256 + n] +
           Wr[((5 + 2) * 256 + kk) * 256 + n] +
           Wr[((5 + 3) * 256 + kk) * 256 + n]) * inv3;
    }
    Bt[i] = f2bf(v);
  } else if (i < 787456) {                // biases
    int j = i - 786432;
    int g = j >> 8, n = j & 255;
    float v;
    if (g == 0)      v = bs[n];                                        // l0 r0
    else if (g == 1) v = (bs[256 + n] + bs[512 + n] + bs[768 + n]) * inv3;   // l0 ch
    else if (g == 2) v = bs[1024 + n];                                 // l0 r4
    else             v = (bs[1280 + 256 + n] + bs[1280 + 512 + n] + bs[1280 + 768 + n]) * inv3; // l1 ch
    bias[j] = v;
  }
}

// ---------------- CSR build (global 3-kernel scan) ----------------
struct P5 { const int* p[5]; };

__global__ void count_kernel(P5 dst, int* __restrict__ cnt) {
  const int COFF[5] = {0, 60000, 100000, 140000, 180000};
  int r = blockIdx.y;
  int e = blockIdx.x * blockDim.x + threadIdx.x;
  if (e < E_EDGES) atomicAdd(&cnt[COFF[r] + dst.p[r][e]], 1);
}

// A: per-block (256 elems) sums
__global__ void scan_a(const int* __restrict__ cnt, int* __restrict__ bsum) {
  int i = blockIdx.x * 256 + threadIdx.x;
  int v = (i < NCNT) ? cnt[i] : 0;
  int lane = threadIdx.x & 63, wv = threadIdx.x >> 6;
  for (int d = 1; d < 64; d <<= 1) v += __shfl_down(v, d);
  __shared__ int ws[4];
  if (lane == 0) ws[wv] = v;
  __syncthreads();
  if (threadIdx.x == 0) bsum[blockIdx.x] = ws[0] + ws[1] + ws[2] + ws[3];
}

// B: exclusive scan of 1094 block sums (one block, 2 elems/thread)
__global__ void scan_b(const int* __restrict__ bsum, int* __restrict__ boff) {
  int t = threadIdx.x;
  int e0 = 2 * t, e1 = 2 * t + 1;
  int v0 = (e0 < NBLK_SCAN) ? bsum[e0] : 0;
  int v1 = (e1 < NBLK_SCAN) ? bsum[e1] : 0;
  __shared__ int lds[1024];
  lds[t] = v0 + v1;
  __syncthreads();
  for (int o = 1; o < 1024; o <<= 1) {
    int add = (t >= o) ? lds[t - o] : 0;
    __syncthreads();
    lds[t] += add;
    __syncthreads();
  }
  int ex = (t == 0) ? 0 : lds[t - 1];
  if (e0 < NBLK_SCAN) boff[e0] = ex;
  if (e1 < NBLK_SCAN) boff[e1] = ex + v0;
}

// C: re-read, block-local exclusive scan + block offset -> S (=rp) and cur
__global__ void scan_c(const int* __restrict__ cnt, const int* __restrict__ boff,
                       int* __restrict__ S, int* __restrict__ cur) {
  int i = blockIdx.x * 256 + threadIdx.x;
  int v = (i < NCNT) ? cnt[i] : 0;
  int lane = threadIdx.x & 63, wv = threadIdx.x >> 6;
  int inc = v;
  for (int d = 1; d < 64; d <<= 1) {
    int y = __shfl_up(inc, d);
    if (lane >= d) inc += y;
  }
  __shared__ int ws[4];
  if (lane == 63) ws[wv] = inc;
  __syncthreads();
  int wex = 0;
  for (int k = 0; k < 4; ++k) wex += (k < wv) ? ws[k] : 0;
  int ex = boff[blockIdx.x] + wex + inc - v;
  if (i < NCNT) { S[i] = ex; cur[i] = ex; }
  if (blockIdx.x == 0 && threadIdx.x == 0) S[NCNT] = 5 * E_EDGES;
}

__global__ void fill_kernel(P5 src, P5 dst, int* __restrict__ cur, int* __restrict__ ssrc) {
  const int COFF[5] = {0, 60000, 100000, 140000, 180000};
  int r = blockIdx.y;
  int e = blockIdx.x * blockDim.x + threadIdx.x;
  if (e < E_EDGES) {
    int d = dst.p[r][e];
    int idx = atomicAdd(&cur[COFF[r] + d], 1);   // global position
    ssrc[idx] = src.p[r][e];
  }
}

// ---------------- mean aggregation: one wave per dst row ----------------
__global__ void agg_kernel(const short* __restrict__ xs, const int* __restrict__ rp,
                           const int* __restrict__ ssrc, short* __restrict__ outb,
                           int n_dst) {
  int wv = (blockIdx.x * blockDim.x + threadIdx.x) >> 6;
  int lane = threadIdx.x & 63;
  if (wv >= n_dst) return;
  int lo = rp[wv], hi = rp[wv + 1];
  float a0 = 0.f, a1 = 0.f, a2 = 0.f, a3 = 0.f;
  for (int e = lo; e < hi; ++e) {
    int s = ssrc[e];
    short4 v = *reinterpret_cast<const short4*>(xs + (size_t)s * 256 + (lane << 2));
    a0 += bf2f(v.x); a1 += bf2f(v.y); a2 += bf2f(v.z); a3 += bf2f(v.w);
  }
  int c = hi - lo; if (c < 1) c = 1;
  float inv = 1.0f / (float)c;
  short4 o;
  o.x = f2bf(a0 * inv); o.y = f2bf(a1 * inv); o.z = f2bf(a2 * inv); o.w = f2bf(a3 * inv);
  *reinterpret_cast<short4*>(outb + (size_t)wv * 256 + (lane << 2)) = o;
}

// ---------------- bf16 MFMA GEMM: out = ReLU([srcs…] @ Bt^T + bias) ----------------
struct Srcs4 { const short* s[4]; };

__global__ __launch_bounds__(256) void gemm_bt(
    Srcs4 srcs, const short* __restrict__ Bt, const float* __restrict__ bias,
    int M, int K, short* __restrict__ outb, float* __restrict__ outf) {
  __shared__ short Asm[128 * 64];
  __shared__ short Bsm[128 * 64];
  const int tid = threadIdx.x;
  const int lane = tid & 63;
  const int w = tid >> 6;
  const int wr = w >> 1, wc = w & 1;
  const int m0 = blockIdx.x * 128;
  const int n0 = blockIdx.y * 128;

  f32x4 acc[4][4];
#pragma unroll
  for (int i = 0; i < 4; ++i)
#pragma unroll
    for (int j = 0; j < 4; ++j) acc[i][j] = (f32x4){0.f, 0.f, 0.f, 0.f};

  for (int k0 = 0; k0 < K; k0 += 64) {
    const short* Aq = srcs.s[k0 >> 8];
    const int kc = k0 & 255;
#pragma unroll
    for (int rr = 0; rr < 4; ++rr) {
      const int rbase = w * 32 + rr * 8;
      const int row = rbase + (lane >> 3);
      const int cs = ((lane & 7) ^ (row & 7)) << 3;   // pre-swizzled source chunk
      int gr = m0 + row; gr = gr < M ? gr : M - 1;
      load_lds16(Aq + (size_t)gr * 256 + kc + cs, &Asm[rbase * 64]);
      load_lds16(Bt + (size_t)(n0 + row) * K + k0 + cs, &Bsm[rbase * 64]);
    }
    __syncthreads();
#pragma unroll
    for (int h = 0; h < 2; ++h) {
      const int cg = (h << 2) + (lane >> 4);          // logical 16B chunk 0..7
      bf16x8 af[4], bfr[4];
#pragma unroll
      for (int mi = 0; mi < 4; ++mi) {
        const int r = wr * 64 + mi * 16 + (lane & 15);
        af[mi] = *reinterpret_cast<const bf16x8*>(&Asm[r * 64 + ((cg ^ (r & 7)) << 3)]);
      }
#pragma unroll
      for (int nj = 0; nj < 4; ++nj) {
        const int r = wc * 64 + nj * 16 + (lane & 15);
        bfr[nj] = *reinterpret_cast<const bf16x8*>(&Bsm[r * 64 + ((cg ^ (r & 7)) << 3)]);
      }
#pragma unroll
      for (int mi = 0; mi < 4; ++mi)
#pragma unroll
        for (int nj = 0; nj < 4; ++nj)
          acc[mi][nj] = __builtin_amdgcn_mfma_f32_16x16x32_bf16(af[mi], bfr[nj], acc[mi][nj], 0, 0, 0);
    }
    __syncthreads();
  }

  const int rb = (lane >> 4) << 2;
  const int cl = lane & 15;
#pragma unroll
  for (int mi = 0; mi < 4; ++mi) {
#pragma unroll
    for (int nj = 0; nj < 4; ++nj) {
      const int col = n0 + wc * 64 + nj * 16 + cl;
      const float bv = bias[col];
#pragma unroll
      for (int j = 0; j < 4; ++j) {
        const int row = m0 + wr * 64 + mi * 16 + rb + j;
        if (row < M) {
          float v = acc[mi][nj][j] + bv;
          v = fmaxf(v, 0.0f);
          if (outf) outf[(size_t)row * 256 + col] = v;
          if (outb) outb[(size_t)row * 256 + col] = f2bf(v);
        }
      }
    }
  }
}

// ---------------- pooling (two-stage) + MLP ----------------
__device__ __forceinline__ int lower_bound(const int* a, int n, int v) {
  int lo = 0, hi = n;
  while (lo < hi) { int mid = (lo + hi) >> 1; if (a[mid] < v) lo = mid + 1; else hi = mid; }
  return lo;
}

__global__ void pool_partial(const float* __restrict__ c2, const int* __restrict__ batch,
                             float* __restrict__ pooled_sum) {
  int r0 = blockIdx.x * 64;
  int t = threadIdx.x;
  float acc = 0.f;
  int prevb = batch[r0];
  for (int i = 0; i < 64; ++i) {
    int r = r0 + i;
    int b = batch[r];
    if (b != prevb) {
      atomicAdd(&pooled_sum[prevb * 256 + t], acc);
      acc = 0.f; prevb = b;
    }
    acc += c2[(size_t)r * 256 + t];
  }
  atomicAdd(&pooled_sum[prevb * 256 + t], acc);
}

__global__ void mlp_kernel(const float* __restrict__ pooled_sum, const int* __restrict__ batch,
                           const float* __restrict__ train,
                           const float* __restrict__ fc1w, const float* __restrict__ fc1b,
                           const float* __restrict__ fc2w, const float* __restrict__ fc2b,
                           float* __restrict__ out) {
  int b = blockIdx.x, t = threadIdx.x;
  __shared__ float x[288];
  __shared__ float hsm[128];
  __shared__ float sinv;
  if (t == 0) {
    int lo = lower_bound(batch, NCH, b);
    int hi = lower_bound(batch, NCH, b + 1);
    int c = hi - lo; if (c < 1) c = 1;
    sinv = 1.0f / (float)c;
  }
  __syncthreads();
  float inv = sinv;
  x[t] = pooled_sum[b * 256 + t] * inv;
  x[128 + t] = pooled_sum[b * 256 + 128 + t] * inv;
  if (t < 32) x[256 + t] = train[b * 32 + t];
  __syncthreads();
  float s = fc1b[t];
  for (int i = 0; i < 288; ++i) s += x[i] * fc1w[i * 128 + t];
  hsm[t] = fmaxf(s, 0.f);
  __syncthreads();
  if (t < 16) {
    float o = fc2b[t];
    for (int i = 0; i < 128; ++i) o += hsm[i] * fc2w[i * 16 + t];
    out[b * 16 + t] = o;
  }
}

// ---------------- launch ----------------
extern "C" void kernel_launch(void* const* d_in, const int* in_sizes, int n_in,
                              void* d_out, int out_size, void* d_ws, size_t ws_size,
                              hipStream_t stream) {
  const float* x_hru = (const float*)d_in[0];
  const float* x_ch  = (const float*)d_in[1];
  const float* x_gw  = (const float*)d_in[2];
  const int* src_swgw = (const int*)d_in[3];
  const int* dst_swgw = (const int*)d_in[4];
  const int* src_hyd  = (const int*)d_in[5];
  const int* dst_hyd  = (const int*)d_in[6];
  const int* src_sw   = (const int*)d_in[7];
  const int* dst_sw   = (const int*)d_in[8];
  const int* src_gwsw = (const int*)d_in[9];
  const int* dst_gwsw = (const int*)d_in[10];
  const int* src_slf  = (const int*)d_in[11];
  const int* dst_slf  = (const int*)d_in[12];
  const int* batch    = (const int*)d_in[13];
  const float* train  = (const float*)d_in[14];
  const float* Wl     = (const float*)d_in[15];
  const float* Wr     = (const float*)d_in[16];
  const float* bs     = (const float*)d_in[17];
  const float* fc1w   = (const float*)d_in[18];
  const float* fc1b   = (const float*)d_in[19];
  const float* fc2w   = (const float*)d_in[20];
  const float* fc2b   = (const float*)d_in[21];
  float* out = (float*)d_out;

  char* ws = (char*)d_ws;
  size_t off = 0;
  auto alloc = [&](size_t bytes) -> void* {
    off = (off + 255) & ~(size_t)255;
    void* p = ws + off;
    off += bytes;
    return p;
  };

  short* xb0h = (short*)alloc((size_t)NHRU * 256 * 2);
  short* xb0c = (short*)alloc((size_t)NCH * 256 * 2);
  short* xb0g = (short*)alloc((size_t)NGW * 256 * 2);
  short* xb1h = (short*)alloc((size_t)NHRU * 256 * 2);
  short* xb1c = (short*)alloc((size_t)NCH * 256 * 2);
  short* xb1g = (short*)alloc((size_t)NGW * 256 * 2);
  short* agg_gw  = (short*)alloc((size_t)NGW * 256 * 2);
  short* agg_c0  = (short*)alloc((size_t)NCH * 256 * 2);
  short* agg_c1  = (short*)alloc((size_t)NCH * 256 * 2);
  short* agg_c2  = (short*)alloc((size_t)NCH * 256 * 2);
  short* agg_hru = (short*)alloc((size_t)NHRU * 256 * 2);
  float* c2f = (float*)alloc((size_t)NCH * 256 * 4);
  int* cnt  = (int*)alloc(NCNT * 4);
  int* rp   = (int*)alloc((NCNT + 1) * 4);       // global exclusive scan S
  int* cur  = (int*)alloc(NCNT * 4);
  int* bsum = (int*)alloc(NBLK_SCAN * 4);
  int* boff = (int*)alloc(NBLK_SCAN * 4);
  int* ssrc = (int*)alloc((size_t)5 * E_EDGES * 4);
  short* BtBuf = (short*)alloc(786432 * 2);
  float* biasBuf = (float*)alloc(1024 * 4);
  float* pooled_sum = (float*)alloc(64 * 256 * 4);

  hipMemsetAsync(cnt, 0, NCNT * 4, stream);
  hipMemsetAsync(pooled_sum, 0, 64 * 256 * 4, stream);

  cvt_kernel<<<NHRU * 256 / 4 / 256, 256, 0, stream>>>(x_hru, xb0h, NHRU * 256 / 4);
  cvt_kernel<<<NCH * 256 / 4 / 256, 256, 0, stream>>>(x_ch, xb0c, NCH * 256 / 4);
  cvt_kernel<<<NGW * 256 / 4 / 256, 256, 0, stream>>>(x_gw, xb0g, NGW * 256 / 4);
  prep_w<<<(787456 + 255) / 256, 256, 0, stream>>>(Wl, Wr, bs, BtBuf, biasBuf);

  P5 dsts; dsts.p[0] = dst_swgw; dsts.p[1] = dst_hyd; dsts.p[2] = dst_sw;
  dsts.p[3] = dst_gwsw; dsts.p[4] = dst_slf;
  P5 srcs; srcs.p[0] = src_swgw; srcs.p[1] = src_hyd; srcs.p[2] = src_sw;
  srcs.p[3] = src_gwsw; srcs.p[4] = src_slf;

  dim3 eg((E_EDGES + 255) / 256, 5);
  count_kernel<<<eg, 256, 0, stream>>>(dsts, cnt);
  scan_a<<<NBLK_SCAN, 256, 0, stream>>>(cnt, bsum);
  scan_b<<<1, 1024, 0, stream>>>(bsum, boff);
  scan_c<<<NBLK_SCAN, 256, 0, stream>>>(cnt, boff, rp, cur);
  fill_kernel<<<eg, 256, 0, stream>>>(srcs, dsts, cur, ssrc);

  const int RP0 = 0, RP1 = 60000, RP2 = 100000, RP3 = 140000, RP4 = 180000;

  // layer 1 aggregations (rp slices are global-coordinate CSR)
  agg_kernel<<<(NGW + 3) / 4, 256, 0, stream>>>(xb0h, rp + RP0, ssrc, agg_gw, NGW);
  agg_kernel<<<(NCH + 3) / 4, 256, 0, stream>>>(xb0c, rp + RP1, ssrc, agg_c0, NCH);
  agg_kernel<<<(NCH + 3) / 4, 256, 0, stream>>>(xb0h, rp + RP2, ssrc, agg_c1, NCH);
  agg_kernel<<<(NCH + 3) / 4, 256, 0, stream>>>(xb0g, rp + RP3, ssrc, agg_c2, NCH);
  agg_kernel<<<(NHRU + 3) / 4, 256, 0, stream>>>(xb0h, rp + RP4, ssrc, agg_hru, NHRU);

  // layer 1 GEMMs
  {
    Srcs4 s{}; s.s[0] = agg_gw; s.s[1] = xb0g;
    gemm_bt<<<dim3((NGW + 127) / 128, 2), 256, 0, stream>>>(s, BtBuf + 0, biasBuf + 0, NGW, 512, xb1g, nullptr);
  }
  {
    Srcs4 s{}; s.s[0] = agg_c0; s.s[1] = agg_c1; s.s[2] = agg_c2; s.s[3] = xb0c;
    gemm_bt<<<dim3((NCH + 127) / 128, 2), 256, 0, stream>>>(s, BtBuf + 131072, biasBuf + 256, NCH, 1024, xb1c, nullptr);
  }
  {
    Srcs4 s{}; s.s[0] = agg_hru; s.s[1] = xb0h;
    gemm_bt<<<dim3((NHRU + 127) / 128, 2), 256, 0, stream>>>(s, BtBuf + 393216, biasBuf + 512, NHRU, 512, xb1h, nullptr);
  }

  // layer 2 aggregations (only channel-dst relations matter)
  agg_kernel<<<(NCH + 3) / 4, 256, 0, stream>>>(xb1c, rp + RP1, ssrc, agg_c0, NCH);
  agg_kernel<<<(NCH + 3) / 4, 256, 0, stream>>>(xb1h, rp + RP2, ssrc, agg_c1, NCH);
  agg_kernel<<<(NCH + 3) / 4, 256, 0, stream>>>(xb1g, rp + RP3, ssrc, agg_c2, NCH);

  // layer 2 channel GEMM -> fp32 c2
  {
    Srcs4 s{}; s.s[0] = agg_c0; s.s[1] = agg_c1; s.s[2] = agg_c2; s.s[3] = xb1c;
    gemm_bt<<<dim3((NCH + 127) / 128, 2), 256, 0, stream>>>(s, BtBuf + 524288, biasBuf + 768, NCH, 1024, nullptr, c2f);
  }

  pool_partial<<<625, 256, 0, stream>>>(c2f, batch, pooled_sum);
  mlp_kernel<<<64, 128, 0, stream>>>(pooled_sum, batch, train, fc1w, fc1b, fc2w, fc2b, out);

  (void)in_sizes; (void)n_in; (void)out_size; (void)ws_size;
}

// Round 4
// 623.206 us; speedup vs baseline: 1.8856x; 1.2242x over previous
//
#include <hip/hip_runtime.h>

#define E_EDGES 250000
#define NHRU 100000
#define NCH  40000
#define NGW  60000
#define NCNT 280000
#define NBLK_SCAN 1094

typedef __attribute__((ext_vector_type(4))) float f32x4;
typedef __attribute__((ext_vector_type(8))) __bf16 bf16x8;
typedef __attribute__((ext_vector_type(8))) short short8;

__device__ __forceinline__ float bf2f(short h) {
  unsigned u = ((unsigned)(unsigned short)h) << 16;
  return __builtin_bit_cast(float, u);
}
__device__ __forceinline__ short f2bf(float f) {
  unsigned u = __builtin_bit_cast(unsigned, f);
  u = u + 0x7fffu + ((u >> 16) & 1u);
  return (short)(u >> 16);
}

__device__ __forceinline__ void load_lds16(const void* g, void* lds) {
  __builtin_amdgcn_global_load_lds(
      (const __attribute__((address_space(1))) unsigned*)g,
      (__attribute__((address_space(3))) unsigned*)lds, 16, 0, 0);
}

// ---------------- fp32 -> bf16 convert (all three matrices, one launch) ----------------
__global__ void cvt3_kernel(const float* __restrict__ a, const float* __restrict__ b,
                            const float* __restrict__ c, short* __restrict__ oa,
                            short* __restrict__ ob, short* __restrict__ oc) {
  int i = blockIdx.x * blockDim.x + threadIdx.x;
  const int n1 = NHRU * 64, n2 = n1 + NCH * 64, n3 = n2 + NGW * 64;
  const float* in; short* out; int j;
  if (i < n1) { in = a; out = oa; j = i; }
  else if (i < n2) { in = b; out = ob; j = i - n1; }
  else if (i < n3) { in = c; out = oc; j = i - n2; }
  else return;
  float4 v = reinterpret_cast<const float4*>(in)[j];
  short4 o;
  o.x = f2bf(v.x); o.y = f2bf(v.y); o.z = f2bf(v.z); o.w = f2bf(v.w);
  reinterpret_cast<short4*>(out)[j] = o;
}

// ---------------- weight prep: transpose + bf16 + fold /3 ----------------
// Bt buffer layout (elems): gw[256][512] @0, ch1[256][1024] @131072,
// hru[256][512] @393216, ch2[256][1024] @524288.  bias: [4][256]
__global__ void prep_w(const float* __restrict__ Wl, const float* __restrict__ Wr,
                       const float* __restrict__ bs, short* __restrict__ Bt,
                       float* __restrict__ bias) {
  int i = blockIdx.x * blockDim.x + threadIdx.x;
  const float inv3 = 1.0f / 3.0f;
  if (i < 131072) {                       // gw: l=0,r=0
    int n = i >> 9, k = i & 511;
    float v = (k < 256) ? Wl[(0 * 256 + k) * 256 + n]
                        : Wr[(0 * 256 + (k - 256)) * 256 + n];
    Bt[i] = f2bf(v);
  } else if (i < 393216) {                // ch l=0: r=1,2,3 then Wr-sum, all /3
    int j = i - 131072;
    int n = j >> 10, k = j & 1023;
    float v;
    if (k < 768) {
      int r = 1 + (k >> 8), kk = k & 255;
      v = Wl[((0 * 5 + r) * 256 + kk) * 256 + n] * inv3;
    } else {
      int kk = k - 768;
      v = (Wr[((0 * 5 + 1) * 256 + kk) * 256 + n] +
           Wr[((0 * 5 + 2) * 256 + kk) * 256 + n] +
           Wr[((0 * 5 + 3) * 256 + kk) * 256 + n]) * inv3;
    }
    Bt[i] = f2bf(v);
  } else if (i < 524288) {                // hru: l=0,r=4
    int j = i - 393216;
    int n = j >> 9, k = j & 511;
    float v = (k < 256) ? Wl[((0 * 5 + 4) * 256 + k) * 256 + n]
                        : Wr[((0 * 5 + 4) * 256 + (k - 256)) * 256 + n];
    Bt[i] = f2bf(v);
  } else if (i < 786432) {                // ch l=1
    int j = i - 524288;
    int n = j >> 10, k = j & 1023;
    float v;
    if (k < 768) {
      int r = 1 + (k >> 8), kk = k & 255;
      v = Wl[((5 + r) * 256 + kk) * 256 + n] * inv3;
    } else {
      int kk = k - 768;
      v = (Wr[((5 + 1) * 256 + kk) * 256 + n] +
           Wr[((5 + 2) * 256 + kk) * 256 + n] +
           Wr[((5 + 3) * 256 + kk) * 256 + n]) * inv3;
    }
    Bt[i] = f2bf(v);
  } else if (i < 787456) {                // biases
    int j = i - 786432;
    int g = j >> 8, n = j & 255;
    float v;
    if (g == 0)      v = bs[n];                                        // l0 r0
    else if (g == 1) v = (bs[256 + n] + bs[512 + n] + bs[768 + n]) * inv3;   // l0 ch
    else if (g == 2) v = bs[1024 + n];                                 // l0 r4
    else             v = (bs[1280 + 256 + n] + bs[1280 + 512 + n] + bs[1280 + 768 + n]) * inv3; // l1 ch
    bias[j] = v;
  }
}

// ---------------- CSR build ----------------
struct P5 { const int* p[5]; };

// pass 1: histogram + per-edge in-row rank (coalesced write)
__global__ void count_rank(P5 dst, int* __restrict__ cnt, int* __restrict__ rank) {
  const int COFF[5] = {0, 60000, 100000, 140000, 180000};
  int r = blockIdx.y;
  int e = blockIdx.x * blockDim.x + threadIdx.x;
  if (e < E_EDGES) {
    int d = dst.p[r][e];
    int rk = atomicAdd(&cnt[COFF[r] + d], 1);
    rank[r * E_EDGES + e] = rk;
  }
}

// A: per-block (256 elems) sums
__global__ void scan_a(const int* __restrict__ cnt, int* __restrict__ bsum) {
  int i = blockIdx.x * 256 + threadIdx.x;
  int v = (i < NCNT) ? cnt[i] : 0;
  int lane = threadIdx.x & 63, wv = threadIdx.x >> 6;
  for (int d = 1; d < 64; d <<= 1) v += __shfl_down(v, d);
  __shared__ int ws[4];
  if (lane == 0) ws[wv] = v;
  __syncthreads();
  if (threadIdx.x == 0) bsum[blockIdx.x] = ws[0] + ws[1] + ws[2] + ws[3];
}

// B: exclusive scan of 1094 block sums (one block, 2 elems/thread)
__global__ void scan_b(const int* __restrict__ bsum, int* __restrict__ boff) {
  int t = threadIdx.x;
  int e0 = 2 * t, e1 = 2 * t + 1;
  int v0 = (e0 < NBLK_SCAN) ? bsum[e0] : 0;
  int v1 = (e1 < NBLK_SCAN) ? bsum[e1] : 0;
  __shared__ int lds[1024];
  lds[t] = v0 + v1;
  __syncthreads();
  for (int o = 1; o < 1024; o <<= 1) {
    int add = (t >= o) ? lds[t - o] : 0;
    __syncthreads();
    lds[t] += add;
    __syncthreads();
  }
  int ex = (t == 0) ? 0 : lds[t - 1];
  if (e0 < NBLK_SCAN) boff[e0] = ex;
  if (e1 < NBLK_SCAN) boff[e1] = ex + v0;
}

// C: re-read, block-local exclusive scan + block offset -> S (=rp)
__global__ void scan_c(const int* __restrict__ cnt, const int* __restrict__ boff,
                       int* __restrict__ S) {
  int i = blockIdx.x * 256 + threadIdx.x;
  int v = (i < NCNT) ? cnt[i] : 0;
  int lane = threadIdx.x & 63, wv = threadIdx.x >> 6;
  int inc = v;
  for (int d = 1; d < 64; d <<= 1) {
    int y = __shfl_up(inc, d);
    if (lane >= d) inc += y;
  }
  __shared__ int ws[4];
  if (lane == 63) ws[wv] = inc;
  __syncthreads();
  int wex = 0;
  for (int k = 0; k < 4; ++k) wex += (k < wv) ? ws[k] : 0;
  int ex = boff[blockIdx.x] + wex + inc - v;
  if (i < NCNT) S[i] = ex;
  if (blockIdx.x == 0 && threadIdx.x == 0) S[NCNT] = 5 * E_EDGES;
}

// pass 2: scatter without atomics (address = rp gather + precomputed rank)
__global__ void scatter_kernel(P5 src, P5 dst, const int* __restrict__ rp,
                               const int* __restrict__ rank, int* __restrict__ ssrc) {
  const int COFF[5] = {0, 60000, 100000, 140000, 180000};
  int r = blockIdx.y;
  int e = blockIdx.x * blockDim.x + threadIdx.x;
  if (e < E_EDGES) {
    int d = dst.p[r][e];
    int idx = rp[COFF[r] + d] + rank[r * E_EDGES + e];
    __builtin_nontemporal_store(src.p[r][e], &ssrc[idx]);
  }
}

// ---------------- mean aggregation: one wave per dst row, 2 edges/iter ----------------
__device__ __forceinline__ void agg_row(const short* __restrict__ xs,
                                        const int* __restrict__ rp,
                                        const int* __restrict__ ssrc,
                                        short* __restrict__ outb,
                                        int wv, int half, int l32) {
  int lo = rp[wv], hi = rp[wv + 1];
  float acc[8] = {0.f, 0.f, 0.f, 0.f, 0.f, 0.f, 0.f, 0.f};
  for (int e = lo + half; e < hi; e += 2) {
    int s = ssrc[e];
    short8 v = *reinterpret_cast<const short8*>(xs + (size_t)s * 256 + l32 * 8);
#pragma unroll
    for (int j = 0; j < 8; ++j) acc[j] += bf2f(v[j]);
  }
#pragma unroll
  for (int j = 0; j < 8; ++j) acc[j] += __shfl_xor(acc[j], 32);
  if (half == 0) {
    int c = hi - lo; if (c < 1) c = 1;
    float inv = 1.0f / (float)c;
    short8 o;
#pragma unroll
    for (int j = 0; j < 8; ++j) o[j] = f2bf(acc[j] * inv);
    *reinterpret_cast<short8*>(outb + (size_t)wv * 256 + l32 * 8) = o;
  }
}

__global__ void agg1_kernel(const short* __restrict__ xs, const int* __restrict__ rp,
                            const int* __restrict__ ssrc, short* __restrict__ outb,
                            int n_dst) {
  int wv = (blockIdx.x * blockDim.x + threadIdx.x) >> 6;
  if (wv >= n_dst) return;
  int lane = threadIdx.x & 63;
  agg_row(xs, rp, ssrc, outb, wv, lane >> 5, lane & 31);
}

// all three channel-dst relations in one pass (hyd src=c, sw src=h, gwsw src=g)
__global__ void agg_ch3_kernel(const short* __restrict__ xc, const short* __restrict__ xh,
                               const short* __restrict__ xg, const int* __restrict__ rp,
                               const int* __restrict__ ssrc,
                               short* __restrict__ o0, short* __restrict__ o1,
                               short* __restrict__ o2) {
  int wv = (blockIdx.x * blockDim.x + threadIdx.x) >> 6;
  if (wv >= NCH) return;
  int lane = threadIdx.x & 63;
  int half = lane >> 5, l32 = lane & 31;
  agg_row(xc, rp + 60000,  ssrc, o0, wv, half, l32);
  agg_row(xh, rp + 100000, ssrc, o1, wv, half, l32);
  agg_row(xg, rp + 140000, ssrc, o2, wv, half, l32);
}

// ---------------- bf16 MFMA GEMM: out = ReLU([srcs…] @ Bt^T + bias) ----------------
struct Srcs4 { const short* s[4]; };

__global__ __launch_bounds__(256) void gemm_bt(
    Srcs4 srcs, const short* __restrict__ Bt, const float* __restrict__ bias,
    int M, int K, short* __restrict__ outb, float* __restrict__ outf) {
  __shared__ short Asm[128 * 64];
  __shared__ short Bsm[128 * 64];
  const int tid = threadIdx.x;
  const int lane = tid & 63;
  const int w = tid >> 6;
  const int wr = w >> 1, wc = w & 1;
  const int m0 = blockIdx.x * 128;
  const int n0 = blockIdx.y * 128;

  f32x4 acc[4][4];
#pragma unroll
  for (int i = 0; i < 4; ++i)
#pragma unroll
    for (int j = 0; j < 4; ++j) acc[i][j] = (f32x4){0.f, 0.f, 0.f, 0.f};

  for (int k0 = 0; k0 < K; k0 += 64) {
    const short* Aq = srcs.s[k0 >> 8];
    const int kc = k0 & 255;
#pragma unroll
    for (int rr = 0; rr < 4; ++rr) {
      const int rbase = w * 32 + rr * 8;
      const int row = rbase + (lane >> 3);
      const int cs = ((lane & 7) ^ (row & 7)) << 3;   // pre-swizzled source chunk
      int gr = m0 + row; gr = gr < M ? gr : M - 1;
      load_lds16(Aq + (size_t)gr * 256 + kc + cs, &Asm[rbase * 64]);
      load_lds16(Bt + (size_t)(n0 + row) * K + k0 + cs, &Bsm[rbase * 64]);
    }
    __syncthreads();
#pragma unroll
    for (int h = 0; h < 2; ++h) {
      const int cg = (h << 2) + (lane >> 4);          // logical 16B chunk 0..7
      bf16x8 af[4], bfr[4];
#pragma unroll
      for (int mi = 0; mi < 4; ++mi) {
        const int r = wr * 64 + mi * 16 + (lane & 15);
        af[mi] = *reinterpret_cast<const bf16x8*>(&Asm[r * 64 + ((cg ^ (r & 7)) << 3)]);
      }
#pragma unroll
      for (int nj = 0; nj < 4; ++nj) {
        const int r = wc * 64 + nj * 16 + (lane & 15);
        bfr[nj] = *reinterpret_cast<const bf16x8*>(&Bsm[r * 64 + ((cg ^ (r & 7)) << 3)]);
      }
#pragma unroll
      for (int mi = 0; mi < 4; ++mi)
#pragma unroll
        for (int nj = 0; nj < 4; ++nj)
          acc[mi][nj] = __builtin_amdgcn_mfma_f32_16x16x32_bf16(af[mi], bfr[nj], acc[mi][nj], 0, 0, 0);
    }
    __syncthreads();
  }

  const int rb = (lane >> 4) << 2;
  const int cl = lane & 15;
#pragma unroll
  for (int mi = 0; mi < 4; ++mi) {
#pragma unroll
    for (int nj = 0; nj < 4; ++nj) {
      const int col = n0 + wc * 64 + nj * 16 + cl;
      const float bv = bias[col];
#pragma unroll
      for (int j = 0; j < 4; ++j) {
        const int row = m0 + wr * 64 + mi * 16 + rb + j;
        if (row < M) {
          float v = acc[mi][nj][j] + bv;
          v = fmaxf(v, 0.0f);
          if (outf) outf[(size_t)row * 256 + col] = v;
          if (outb) outb[(size_t)row * 256 + col] = f2bf(v);
        }
      }
    }
  }
}

// ---------------- pooling (two-stage) + MLP ----------------
__device__ __forceinline__ int lower_bound(const int* a, int n, int v) {
  int lo = 0, hi = n;
  while (lo < hi) { int mid = (lo + hi) >> 1; if (a[mid] < v) lo = mid + 1; else hi = mid; }
  return lo;
}

__global__ void pool_partial(const float* __restrict__ c2, const int* __restrict__ batch,
                             float* __restrict__ pooled_sum) {
  int r0 = blockIdx.x * 64;
  int t = threadIdx.x;
  float acc = 0.f;
  int prevb = batch[r0];
  for (int i = 0; i < 64; ++i) {
    int r = r0 + i;
    int b = batch[r];
    if (b != prevb) {
      atomicAdd(&pooled_sum[prevb * 256 + t], acc);
      acc = 0.f; prevb = b;
    }
    acc += c2[(size_t)r * 256 + t];
  }
  atomicAdd(&pooled_sum[prevb * 256 + t], acc);
}

__global__ void mlp_kernel(const float* __restrict__ pooled_sum, const int* __restrict__ batch,
                           const float* __restrict__ train,
                           const float* __restrict__ fc1w, const float* __restrict__ fc1b,
                           const float* __restrict__ fc2w, const float* __restrict__ fc2b,
                           float* __restrict__ out) {
  int b = blockIdx.x, t = threadIdx.x;
  __shared__ float x[288];
  __shared__ float hsm[128];
  __shared__ float sinv;
  if (t == 0) {
    int lo = lower_bound(batch, NCH, b);
    int hi = lower_bound(batch, NCH, b + 1);
    int c = hi - lo; if (c < 1) c = 1;
    sinv = 1.0f / (float)c;
  }
  __syncthreads();
  float inv = sinv;
  x[t] = pooled_sum[b * 256 + t] * inv;
  x[128 + t] = pooled_sum[b * 256 + 128 + t] * inv;
  if (t < 32) x[256 + t] = train[b * 32 + t];
  __syncthreads();
  float s = fc1b[t];
  for (int i = 0; i < 288; ++i) s += x[i] * fc1w[i * 128 + t];
  hsm[t] = fmaxf(s, 0.f);
  __syncthreads();
  if (t < 16) {
    float o = fc2b[t];
    for (int i = 0; i < 128; ++i) o += hsm[i] * fc2w[i * 16 + t];
    out[b * 16 + t] = o;
  }
}

// ---------------- launch ----------------
extern "C" void kernel_launch(void* const* d_in, const int* in_sizes, int n_in,
                              void* d_out, int out_size, void* d_ws, size_t ws_size,
                              hipStream_t stream) {
  const float* x_hru = (const float*)d_in[0];
  const float* x_ch  = (const float*)d_in[1];
  const float* x_gw  = (const float*)d_in[2];
  const int* src_swgw = (const int*)d_in[3];
  const int* dst_swgw = (const int*)d_in[4];
  const int* src_hyd  = (const int*)d_in[5];
  const int* dst_hyd  = (const int*)d_in[6];
  const int* src_sw   = (const int*)d_in[7];
  const int* dst_sw   = (const int*)d_in[8];
  const int* src_gwsw = (const int*)d_in[9];
  const int* dst_gwsw = (const int*)d_in[10];
  const int* src_slf  = (const int*)d_in[11];
  const int* dst_slf  = (const int*)d_in[12];
  const int* batch    = (const int*)d_in[13];
  const float* train  = (const float*)d_in[14];
  const float* Wl     = (const float*)d_in[15];
  const float* Wr     = (const float*)d_in[16];
  const float* bs     = (const float*)d_in[17];
  const float* fc1w   = (const float*)d_in[18];
  const float* fc1b   = (const float*)d_in[19];
  const float* fc2w   = (const float*)d_in[20];
  const float* fc2b   = (const float*)d_in[21];
  float* out = (float*)d_out;

  char* ws = (char*)d_ws;
  size_t off = 0;
  auto alloc = [&](size_t bytes) -> void* {
    off = (off + 255) & ~(size_t)255;
    void* p = ws + off;
    off += bytes;
    return p;
  };

  short* xb0h = (short*)alloc((size_t)NHRU * 256 * 2);
  short* xb0c = (short*)alloc((size_t)NCH * 256 * 2);
  short* xb0g = (short*)alloc((size_t)NGW * 256 * 2);
  short* xb1h = (short*)alloc((size_t)NHRU * 256 * 2);
  short* xb1c = (short*)alloc((size_t)NCH * 256 * 2);
  short* xb1g = (short*)alloc((size_t)NGW * 256 * 2);
  short* agg_gw  = (short*)alloc((size_t)NGW * 256 * 2);
  short* agg_c0  = (short*)alloc((size_t)NCH * 256 * 2);
  short* agg_c1  = (short*)alloc((size_t)NCH * 256 * 2);
  short* agg_c2  = (short*)alloc((size_t)NCH * 256 * 2);
  short* agg_hru = (short*)alloc((size_t)NHRU * 256 * 2);
  float* c2f = (float*)alloc((size_t)NCH * 256 * 4);
  int* cnt  = (int*)alloc(NCNT * 4);
  int* rp   = (int*)alloc((NCNT + 1) * 4);       // global exclusive scan S
  int* rank = (int*)alloc((size_t)5 * E_EDGES * 4);
  int* bsum = (int*)alloc(NBLK_SCAN * 4);
  int* boff = (int*)alloc(NBLK_SCAN * 4);
  int* ssrc = (int*)alloc((size_t)5 * E_EDGES * 4);
  short* BtBuf = (short*)alloc(786432 * 2);
  float* biasBuf = (float*)alloc(1024 * 4);
  float* pooled_sum = (float*)alloc(64 * 256 * 4);

  hipMemsetAsync(cnt, 0, NCNT * 4, stream);
  hipMemsetAsync(pooled_sum, 0, 64 * 256 * 4, stream);

  const int NCVT = (NHRU + NCH + NGW) * 64;
  cvt3_kernel<<<(NCVT + 255) / 256, 256, 0, stream>>>(x_hru, x_ch, x_gw, xb0h, xb0c, xb0g);
  prep_w<<<(787456 + 255) / 256, 256, 0, stream>>>(Wl, Wr, bs, BtBuf, biasBuf);

  P5 dsts; dsts.p[0] = dst_swgw; dsts.p[1] = dst_hyd; dsts.p[2] = dst_sw;
  dsts.p[3] = dst_gwsw; dsts.p[4] = dst_slf;
  P5 srcs; srcs.p[0] = src_swgw; srcs.p[1] = src_hyd; srcs.p[2] = src_sw;
  srcs.p[3] = src_gwsw; srcs.p[4] = src_slf;

  dim3 eg((E_EDGES + 255) / 256, 5);
  count_rank<<<eg, 256, 0, stream>>>(dsts, cnt, rank);
  scan_a<<<NBLK_SCAN, 256, 0, stream>>>(cnt, bsum);
  scan_b<<<1, 1024, 0, stream>>>(bsum, boff);
  scan_c<<<NBLK_SCAN, 256, 0, stream>>>(cnt, boff, rp);
  scatter_kernel<<<eg, 256, 0, stream>>>(srcs, dsts, rp, rank, ssrc);

  const int RP0 = 0, RP4 = 180000;

  // layer 1 aggregations
  agg1_kernel<<<(NGW + 3) / 4, 256, 0, stream>>>(xb0h, rp + RP0, ssrc, agg_gw, NGW);
  agg_ch3_kernel<<<(NCH + 3) / 4, 256, 0, stream>>>(xb0c, xb0h, xb0g, rp, ssrc, agg_c0, agg_c1, agg_c2);
  agg1_kernel<<<(NHRU + 3) / 4, 256, 0, stream>>>(xb0h, rp + RP4, ssrc, agg_hru, NHRU);

  // layer 1 GEMMs
  {
    Srcs4 s{}; s.s[0] = agg_gw; s.s[1] = xb0g;
    gemm_bt<<<dim3((NGW + 127) / 128, 2), 256, 0, stream>>>(s, BtBuf + 0, biasBuf + 0, NGW, 512, xb1g, nullptr);
  }
  {
    Srcs4 s{}; s.s[0] = agg_c0; s.s[1] = agg_c1; s.s[2] = agg_c2; s.s[3] = xb0c;
    gemm_bt<<<dim3((NCH + 127) / 128, 2), 256, 0, stream>>>(s, BtBuf + 131072, biasBuf + 256, NCH, 1024, xb1c, nullptr);
  }
  {
    Srcs4 s{}; s.s[0] = agg_hru; s.s[1] = xb0h;
    gemm_bt<<<dim3((NHRU + 127) / 128, 2), 256, 0, stream>>>(s, BtBuf + 393216, biasBuf + 512, NHRU, 512, xb1h, nullptr);
  }

  // layer 2 aggregations (only channel-dst relations matter)
  agg_ch3_kernel<<<(NCH + 3) / 4, 256, 0, stream>>>(xb1c, xb1h, xb1g, rp, ssrc, agg_c0, agg_c1, agg_c2);

  // layer 2 channel GEMM -> fp32 c2
  {
    Srcs4 s{}; s.s[0] = agg_c0; s.s[1] = agg_c1; s.s[2] = agg_c2; s.s[3] = xb1c;
    gemm_bt<<<dim3((NCH + 127) / 128, 2), 256, 0, stream>>>(s, BtBuf + 524288, biasBuf + 768, NCH, 1024, nullptr, c2f);
  }

  pool_partial<<<625, 256, 0, stream>>>(c2f, batch, pooled_sum);
  mlp_kernel<<<64, 128, 0, stream>>>(pooled_sum, batch, train, fc1w, fc1b, fc2w, fc2b, out);

  (void)in_sizes; (void)n_in; (void)out_size; (void)ws_size;
}